// Round 1
// baseline (1154.757 us; speedup 1.0000x reference)
//
#include <hip/hip_runtime.h>

// DeltaNet fused pipeline, round 0 (correctness-first):
//   k_cast:    x fp32 -> bf16
//   k_transw:  Wq/Wk/Wv -> Wt (N x K bf16, concat), Wo -> Wot
//   k_beta:    beta = clip(sigmoid(x@Wg + bg))
//   k_gemm:    bf16 MFMA 128x128 tile GEMM (QKV fused, N=6144), bf16 out
//   k_ropephi: RoPE + (elu+1) in-place on q,k halves of qkv buffer
//   k_recur:   sequential deltanet recurrence, e-column-split across 288 blocks,
//              writes raw numer (fp32) + invden; denom folded in as virtual v=1 col
//   k_gemm:    out = (numer*invden) @ Wot + bo  (scale+cast fused into A staging)

typedef __attribute__((ext_vector_type(8))) short short8;
typedef __attribute__((ext_vector_type(4))) float f32x4;

__device__ __forceinline__ unsigned short f2bf(float f) {
  unsigned u = __float_as_uint(f);
  u += 0x7fffu + ((u >> 16) & 1u);   // RNE
  return (unsigned short)(u >> 16);
}
__device__ __forceinline__ float bf2f(unsigned short s) {
  return __uint_as_float(((unsigned)s) << 16);
}
__device__ __forceinline__ float phi_elu1(float x) {
  return x > 0.f ? x + 1.f : expf(x);
}

// ---------------- cast x -> bf16 ----------------
__global__ __launch_bounds__(256)
void k_cast(const float* __restrict__ x, unsigned short* __restrict__ xb) {
  int i = (blockIdx.x * 256 + threadIdx.x) * 4;
  float4 f = *(const float4*)(x + i);
  uint2 p;
  p.x = (unsigned)f2bf(f.x) | ((unsigned)f2bf(f.y) << 16);
  p.y = (unsigned)f2bf(f.z) | ((unsigned)f2bf(f.w) << 16);
  *(uint2*)(xb + i) = p;
}

// ---------------- transpose+cast W (K x N) -> (N x K) bf16 ----------------
__global__ __launch_bounds__(256)
void k_transw(const float* __restrict__ Wq, const float* __restrict__ Wk,
              const float* __restrict__ Wv, const float* __restrict__ Wo,
              unsigned short* __restrict__ Wt, unsigned short* __restrict__ Wot) {
  const int z = blockIdx.z;
  const float* W = (z == 0) ? Wq : (z == 1) ? Wk : (z == 2) ? Wv : Wo;
  unsigned short* out = (z < 3) ? (Wt + (size_t)z * 2048 * 2048) : Wot;
  __shared__ float tile[64][65];
  const int n0 = blockIdx.x * 64;
  const int k0 = blockIdx.y * 64;
  const int tx = threadIdx.x & 63;
  const int ty = threadIdx.x >> 6;
#pragma unroll
  for (int rl = 0; rl < 16; ++rl) {
    int kk = rl * 4 + ty;
    tile[kk][tx] = W[(size_t)(k0 + kk) * 2048 + n0 + tx];
  }
  __syncthreads();
#pragma unroll
  for (int rl = 0; rl < 16; ++rl) {
    int nn = rl * 4 + ty;
    out[(size_t)(n0 + nn) * 2048 + k0 + tx] = f2bf(tile[tx][nn]);
  }
}

// ---------------- beta = clip(sigmoid(x@Wg + bg)) ----------------
__global__ __launch_bounds__(256)
void k_beta(const float* __restrict__ x, const float* __restrict__ Wg,
            const float* __restrict__ bg, float* __restrict__ beta) {
  __shared__ float sm[256 * 17];
  const int m = blockIdx.x;
  const int tid = threadIdx.x;
  float acc[16];
#pragma unroll
  for (int hh = 0; hh < 16; ++hh) acc[hh] = 0.f;
  const float* xr = x + (size_t)m * 2048;
  for (int k = tid; k < 2048; k += 256) {
    float xv = xr[k];
    const float4* wr = (const float4*)(Wg + (size_t)k * 16);
    float4 w0 = wr[0], w1 = wr[1], w2 = wr[2], w3 = wr[3];
    acc[0]  = fmaf(xv, w0.x, acc[0]);  acc[1]  = fmaf(xv, w0.y, acc[1]);
    acc[2]  = fmaf(xv, w0.z, acc[2]);  acc[3]  = fmaf(xv, w0.w, acc[3]);
    acc[4]  = fmaf(xv, w1.x, acc[4]);  acc[5]  = fmaf(xv, w1.y, acc[5]);
    acc[6]  = fmaf(xv, w1.z, acc[6]);  acc[7]  = fmaf(xv, w1.w, acc[7]);
    acc[8]  = fmaf(xv, w2.x, acc[8]);  acc[9]  = fmaf(xv, w2.y, acc[9]);
    acc[10] = fmaf(xv, w2.z, acc[10]); acc[11] = fmaf(xv, w2.w, acc[11]);
    acc[12] = fmaf(xv, w3.x, acc[12]); acc[13] = fmaf(xv, w3.y, acc[13]);
    acc[14] = fmaf(xv, w3.z, acc[14]); acc[15] = fmaf(xv, w3.w, acc[15]);
  }
#pragma unroll
  for (int hh = 0; hh < 16; ++hh) sm[tid * 17 + hh] = acc[hh];
  __syncthreads();
  for (int s = 128; s > 0; s >>= 1) {
    if (tid < s) {
#pragma unroll
      for (int hh = 0; hh < 16; ++hh) sm[tid * 17 + hh] += sm[(tid + s) * 17 + hh];
    }
    __syncthreads();
  }
  if (tid < 16) {
    float val = sm[tid] + bg[tid];
    float bv = 1.f / (1.f + expf(-val));
    bv = fminf(fmaxf(bv, 0.8f), 0.9995f);
    beta[(size_t)m * 16 + tid] = bv;
  }
}

// ---------------- bf16 MFMA GEMM: C[M,N] = A[M,K] @ Bt[N,K]^T ----------------
// A_SCALED_F32: A is fp32, scaled by invden[row, k>>7], cast to bf16 in staging.
template <bool A_SCALED_F32, bool OUT_BF16, bool ADD_BIAS>
__global__ __launch_bounds__(256)
void k_gemm(const void* __restrict__ Aptr, const unsigned short* __restrict__ Bt,
            void* __restrict__ Cptr, const float* __restrict__ invden,
            const float* __restrict__ bias, int M, int N, int K, int ldA, int ldC) {
  __shared__ short As[128][40];  // +8 pad: 80B rows, 16B aligned, 2-way banks (free)
  __shared__ short Bs[128][40];
  const int tid = threadIdx.x;
  const int n0 = blockIdx.x * 128;
  const int m0 = blockIdx.y * 128;
  const int lane = tid & 63;
  const int w = tid >> 6;
  const int wm = w >> 1, wn = w & 1;
  const int q = lane >> 4, r = lane & 15;

  f32x4 acc[4][4];
#pragma unroll
  for (int i = 0; i < 4; ++i)
#pragma unroll
    for (int j = 0; j < 4; ++j) acc[i][j] = (f32x4){0.f, 0.f, 0.f, 0.f};

  for (int kt = 0; kt < K; kt += 32) {
    __syncthreads();
#pragma unroll
    for (int i = 0; i < 2; ++i) {
      int c = tid + i * 256;     // 0..511
      int row = c >> 2;          // 0..127
      int kc = (c & 3) * 8;      // 0,8,16,24
      if (A_SCALED_F32) {
        const float* Af = (const float*)Aptr;
        const float* ap = Af + (size_t)(m0 + row) * ldA + kt + kc;
        float4 fa = *(const float4*)ap;
        float4 fb = *(const float4*)(ap + 4);
        float sc = invden[(size_t)(m0 + row) * 16 + ((kt + kc) >> 7)];
        uint2 q0, q1;
        q0.x = (unsigned)f2bf(fa.x * sc) | ((unsigned)f2bf(fa.y * sc) << 16);
        q0.y = (unsigned)f2bf(fa.z * sc) | ((unsigned)f2bf(fa.w * sc) << 16);
        q1.x = (unsigned)f2bf(fb.x * sc) | ((unsigned)f2bf(fb.y * sc) << 16);
        q1.y = (unsigned)f2bf(fb.z * sc) | ((unsigned)f2bf(fb.w * sc) << 16);
        *(uint2*)&As[row][kc] = q0;
        *(uint2*)&As[row][kc + 4] = q1;
      } else {
        const unsigned short* Ab = (const unsigned short*)Aptr;
        *(int4*)&As[row][kc] = *(const int4*)(Ab + (size_t)(m0 + row) * ldA + kt + kc);
      }
      *(int4*)&Bs[row][kc] = *(const int4*)(Bt + (size_t)(n0 + row) * K + kt + kc);
    }
    __syncthreads();
    short8 af[4], bfr[4];
#pragma unroll
    for (int i = 0; i < 4; ++i)
      af[i] = *(const short8*)&As[wm * 64 + i * 16 + r][q * 8];
#pragma unroll
    for (int j = 0; j < 4; ++j)
      bfr[j] = *(const short8*)&Bs[wn * 64 + j * 16 + r][q * 8];
#pragma unroll
    for (int i = 0; i < 4; ++i)
#pragma unroll
      for (int j = 0; j < 4; ++j)
        acc[i][j] = __builtin_amdgcn_mfma_f32_16x16x32_bf16(af[i], bfr[j], acc[i][j], 0, 0, 0);
  }
  // epilogue: D[row=(lane>>4)*4+rr][col=lane&15]
#pragma unroll
  for (int i = 0; i < 4; ++i) {
#pragma unroll
    for (int j = 0; j < 4; ++j) {
#pragma unroll
      for (int rr = 0; rr < 4; ++rr) {
        int mi = m0 + wm * 64 + i * 16 + q * 4 + rr;
        int ni = n0 + wn * 64 + j * 16 + r;
        float val = acc[i][j][rr];
        if (ADD_BIAS) val += bias[ni];
        if (OUT_BF16)
          ((unsigned short*)Cptr)[(size_t)mi * ldC + ni] = f2bf(val);
        else
          ((float*)Cptr)[(size_t)mi * ldC + ni] = val;
      }
    }
  }
}

// ---------------- RoPE + phi, in place on q,k of qkv (bf16, ld=6144) ----------------
__global__ __launch_bounds__(256)
void k_ropephi(unsigned short* __restrict__ qkv) {
  int id = blockIdx.x * 256 + threadIdx.x;   // < 4096*16*64
  int e = id & 63;
  int r2 = id >> 6;
  int h = r2 & 15;
  int m = r2 >> 4;       // b*2048 + t
  int t = m & 2047;
  float inv = expf((float)e * -0.14391156831212787f);  // 10000^(-e/64)
  float ang = (float)t * inv;
  float s, c;
  sincosf(ang, &s, &c);
  size_t base = (size_t)m * 6144 + (size_t)h * 128 + e;
  // q
  float qe = bf2f(qkv[base]), qo = bf2f(qkv[base + 64]);
  float a0 = qe * c - qo * s, a1 = qe * s + qo * c;
  qkv[base] = f2bf(phi_elu1(a0));
  qkv[base + 64] = f2bf(phi_elu1(a1));
  // k (col offset 2048)
  float ke = bf2f(qkv[base + 2048]), ko = bf2f(qkv[base + 2048 + 64]);
  a0 = ke * c - ko * s;
  a1 = ke * s + ko * c;
  qkv[base + 2048] = f2bf(phi_elu1(a0));
  qkv[base + 2048 + 64] = f2bf(phi_elu1(a1));
}

// ---------------- sequential recurrence ----------------
// grid (9, 32): x = e-chunk (8 x 16 cols + 1 z/denom chunk), y = (b,h)
// thread: dg = tid&15 owns d in [dg*8, dg*8+8); eg = tid>>4 owns e = e0+eg
__global__ __launch_bounds__(256)
void k_recur(const unsigned short* __restrict__ qkv, const float* __restrict__ beta,
             float* __restrict__ numer, float* __restrict__ invden) {
  const int ec = blockIdx.x;  // 0..8
  const int bh = blockIdx.y;  // 0..31
  const int b = bh >> 4, h = bh & 15;
  const int tid = threadIdx.x;
  const int dg = tid & 15;
  const int eg = tid >> 4;
  const int e0 = ec * 16;
  const bool ZM = (ec == 8);

  __shared__ unsigned short pq_s[16][128];
  __shared__ unsigned short pk_s[16][128];
  __shared__ unsigned short v_s[16][16];
  __shared__ float b_s[16];

  float S[8];
#pragma unroll
  for (int j = 0; j < 8; ++j) S[j] = 0.f;

  const size_t rowbase = ((size_t)b * 2048) * 6144 + (size_t)h * 128;
  const int ts_l = tid >> 4, ch = tid & 15;  // staging coords

  for (int t0 = 0; t0 < 2048; t0 += 16) {
    __syncthreads();
    {
      size_t rb = rowbase + (size_t)(t0 + ts_l) * 6144;
      *(int4*)&pq_s[ts_l][ch * 8] = *(const int4*)(qkv + rb + ch * 8);
      *(int4*)&pk_s[ts_l][ch * 8] = *(const int4*)(qkv + rb + 2048 + ch * 8);
      v_s[ts_l][ch] = ZM ? (unsigned short)0x3F80 : qkv[rb + 4096 + e0 + ch];
      if (tid < 16) b_s[tid] = beta[(size_t)(b * 2048 + t0 + tid) * 16 + h];
    }
    __syncthreads();
#pragma unroll 4
    for (int ts = 0; ts < 16; ++ts) {
      float bb = b_s[ts];
      float ve = bf2f(v_s[ts][eg]);
      short8 pk8 = *(const short8*)&pk_s[ts][dg * 8];
      short8 pq8 = *(const short8*)&pq_s[ts][dg * 8];
      float np0 = 0.f, np1 = 0.f;
#pragma unroll
      for (int j = 0; j < 8; ++j) {
        float pk = bf2f((unsigned short)pk8[j]);
        float pq = bf2f((unsigned short)pq8[j]);
        S[j] = fmaf(S[j], bb, pk * ve);   // S = S*b + k v^T
        if (j & 1) np1 = fmaf(pq, S[j], np1);
        else       np0 = fmaf(pq, S[j], np0);
      }
      float np = np0 + np1;
      np += __shfl_xor(np, 1, 64);
      np += __shfl_xor(np, 2, 64);
      np += __shfl_xor(np, 4, 64);
      np += __shfl_xor(np, 8, 64);
      if (dg == 0) {
        int m = b * 2048 + t0 + ts;
        if (!ZM)
          numer[(size_t)m * 2048 + h * 128 + e0 + eg] = np;
        else if (eg == 0)
          invden[(size_t)m * 16 + h] = 1.f / (np + 1e-6f);  // denom = pq.z + EPS
      }
    }
  }
}

extern "C" void kernel_launch(void* const* d_in, const int* in_sizes, int n_in,
                              void* d_out, int out_size, void* d_ws, size_t ws_size,
                              hipStream_t stream) {
  const float* x  = (const float*)d_in[0];
  const float* Wq = (const float*)d_in[1];
  const float* Wk = (const float*)d_in[2];
  const float* Wv = (const float*)d_in[3];
  const float* Wg = (const float*)d_in[4];
  const float* bg = (const float*)d_in[5];
  const float* Wo = (const float*)d_in[6];
  const float* bo = (const float*)d_in[7];

  // workspace layout (bytes), total 134,742,016
  char* ws = (char*)d_ws;
  unsigned short* xb    = (unsigned short*)(ws);                 // 16,777,216  x bf16 [4096][2048]
  unsigned short* Wt    = (unsigned short*)(ws + 16777216);      // 25,165,824  [6144][2048] bf16 (N x K)
  unsigned short* Wot   = (unsigned short*)(ws + 41943040);      //  8,388,608  [2048][2048] bf16 (N x K)
  unsigned short* qkvb  = (unsigned short*)(ws + 50331648);      // 50,331,648  [4096][6144] bf16
  float*          beta  = (float*)(ws + 100663296);              //    262,144  [4096][16]
  float*          invd  = (float*)(ws + 100925440);              //    262,144  [4096][16]
  float*          numer = (float*)(ws + 101187584);              // 33,554,432  [4096][2048] fp32

  k_cast<<<8192, 256, 0, stream>>>(x, xb);
  k_transw<<<dim3(32, 32, 4), 256, 0, stream>>>(Wq, Wk, Wv, Wo, Wt, Wot);
  k_beta<<<4096, 256, 0, stream>>>(x, Wg, bg, beta);
  k_gemm<false, true, false><<<dim3(48, 32), 256, 0, stream>>>(
      xb, Wt, qkvb, nullptr, nullptr, 4096, 6144, 2048, 2048, 6144);
  k_ropephi<<<16384, 256, 0, stream>>>(qkvb);
  k_recur<<<dim3(9, 32), 256, 0, stream>>>(qkvb, beta, numer, invd);
  k_gemm<true, false, true><<<dim3(16, 32), 256, 0, stream>>>(
      numer, Wot, d_out, invd, bo, 4096, 2048, 2048, 2048, 2048);
}

// Round 2
// 494.289 us; speedup vs baseline: 2.3362x; 2.3362x over previous
//
#include <hip/hip_runtime.h>

// DeltaNet fused pipeline, round 1: chunk-parallel recurrence.
//   k_cast:   x fp32 -> bf16
//   k_transw: Wq/Wk/Wv -> Wt (N x K bf16), Wo -> Wot
//   k_beta:   beta = clip(sigmoid(x@Wg + bg))
//   k_gemm:   bf16 MFMA 128x128 tile GEMM (QKV fused, N=6144) -> qkv bf16
//   k_prep:   per (bh,chunk=64): G prefix-product, RoPE+phi fused, writes
//             Qt = G*phi(rope(q)) [bh][ch][64][128], Ktg = (phi(rope(k))/G)^T
//             [bh][ch][128][64], Ag = tril(Qt Kt^T) bf16 [bh][ch][64][64] (MFMA)
//   k_scan:   per (eb 0..8, bh): sequential over 32 chunks, state S (128x16)
//             fp32 in MFMA accumulators: numer = A V + Qt S0 (MFMA),
//             S' = gC*(S0 + Kt^T V) (MFMA, fp32 C). eb==8 = z/denom column.
//   k_gemm:   out = (numer*invden) @ Wot + bo

typedef __attribute__((ext_vector_type(8))) short short8;
typedef __attribute__((ext_vector_type(4))) float f32x4;

__device__ __forceinline__ unsigned short f2bf(float f) {
  unsigned u = __float_as_uint(f);
  u += 0x7fffu + ((u >> 16) & 1u);   // RNE
  return (unsigned short)(u >> 16);
}
__device__ __forceinline__ float bf2f(unsigned short s) {
  return __uint_as_float(((unsigned)s) << 16);
}
__device__ __forceinline__ float phi_elu1(float x) {
  return x > 0.f ? x + 1.f : expf(x);
}

// ---------------- cast x -> bf16 ----------------
__global__ __launch_bounds__(256)
void k_cast(const float* __restrict__ x, unsigned short* __restrict__ xb) {
  int i = (blockIdx.x * 256 + threadIdx.x) * 4;
  float4 f = *(const float4*)(x + i);
  uint2 p;
  p.x = (unsigned)f2bf(f.x) | ((unsigned)f2bf(f.y) << 16);
  p.y = (unsigned)f2bf(f.z) | ((unsigned)f2bf(f.w) << 16);
  *(uint2*)(xb + i) = p;
}

// ---------------- transpose+cast W (K x N) -> (N x K) bf16 ----------------
__global__ __launch_bounds__(256)
void k_transw(const float* __restrict__ Wq, const float* __restrict__ Wk,
              const float* __restrict__ Wv, const float* __restrict__ Wo,
              unsigned short* __restrict__ Wt, unsigned short* __restrict__ Wot) {
  const int z = blockIdx.z;
  const float* W = (z == 0) ? Wq : (z == 1) ? Wk : (z == 2) ? Wv : Wo;
  unsigned short* out = (z < 3) ? (Wt + (size_t)z * 2048 * 2048) : Wot;
  __shared__ float tile[64][65];
  const int n0 = blockIdx.x * 64;
  const int k0 = blockIdx.y * 64;
  const int tx = threadIdx.x & 63;
  const int ty = threadIdx.x >> 6;
#pragma unroll
  for (int rl = 0; rl < 16; ++rl) {
    int kk = rl * 4 + ty;
    tile[kk][tx] = W[(size_t)(k0 + kk) * 2048 + n0 + tx];
  }
  __syncthreads();
#pragma unroll
  for (int rl = 0; rl < 16; ++rl) {
    int nn = rl * 4 + ty;
    out[(size_t)(n0 + nn) * 2048 + k0 + tx] = f2bf(tile[tx][nn]);
  }
}

// ---------------- beta = clip(sigmoid(x@Wg + bg)) ----------------
__global__ __launch_bounds__(256)
void k_beta(const float* __restrict__ x, const float* __restrict__ Wg,
            const float* __restrict__ bg, float* __restrict__ beta) {
  __shared__ float sm[256 * 17];
  const int m = blockIdx.x;
  const int tid = threadIdx.x;
  float acc[16];
#pragma unroll
  for (int hh = 0; hh < 16; ++hh) acc[hh] = 0.f;
  const float* xr = x + (size_t)m * 2048;
  for (int k = tid; k < 2048; k += 256) {
    float xv = xr[k];
    const float4* wr = (const float4*)(Wg + (size_t)k * 16);
    float4 w0 = wr[0], w1 = wr[1], w2 = wr[2], w3 = wr[3];
    acc[0]  = fmaf(xv, w0.x, acc[0]);  acc[1]  = fmaf(xv, w0.y, acc[1]);
    acc[2]  = fmaf(xv, w0.z, acc[2]);  acc[3]  = fmaf(xv, w0.w, acc[3]);
    acc[4]  = fmaf(xv, w1.x, acc[4]);  acc[5]  = fmaf(xv, w1.y, acc[5]);
    acc[6]  = fmaf(xv, w1.z, acc[6]);  acc[7]  = fmaf(xv, w1.w, acc[7]);
    acc[8]  = fmaf(xv, w2.x, acc[8]);  acc[9]  = fmaf(xv, w2.y, acc[9]);
    acc[10] = fmaf(xv, w2.z, acc[10]); acc[11] = fmaf(xv, w2.w, acc[11]);
    acc[12] = fmaf(xv, w3.x, acc[12]); acc[13] = fmaf(xv, w3.y, acc[13]);
    acc[14] = fmaf(xv, w3.z, acc[14]); acc[15] = fmaf(xv, w3.w, acc[15]);
  }
#pragma unroll
  for (int hh = 0; hh < 16; ++hh) sm[tid * 17 + hh] = acc[hh];
  __syncthreads();
  for (int s = 128; s > 0; s >>= 1) {
    if (tid < s) {
#pragma unroll
      for (int hh = 0; hh < 16; ++hh) sm[tid * 17 + hh] += sm[(tid + s) * 17 + hh];
    }
    __syncthreads();
  }
  if (tid < 16) {
    float val = sm[tid] + bg[tid];
    float bv = 1.f / (1.f + expf(-val));
    bv = fminf(fmaxf(bv, 0.8f), 0.9995f);
    beta[(size_t)m * 16 + tid] = bv;
  }
}

// ---------------- bf16 MFMA GEMM: C[M,N] = A[M,K] @ Bt[N,K]^T ----------------
template <bool A_SCALED_F32, bool OUT_BF16, bool ADD_BIAS>
__global__ __launch_bounds__(256)
void k_gemm(const void* __restrict__ Aptr, const unsigned short* __restrict__ Bt,
            void* __restrict__ Cptr, const float* __restrict__ invden,
            const float* __restrict__ bias, int M, int N, int K, int ldA, int ldC) {
  __shared__ short As[128][40];
  __shared__ short Bs[128][40];
  const int tid = threadIdx.x;
  const int n0 = blockIdx.x * 128;
  const int m0 = blockIdx.y * 128;
  const int lane = tid & 63;
  const int w = tid >> 6;
  const int wm = w >> 1, wn = w & 1;
  const int q = lane >> 4, r = lane & 15;

  f32x4 acc[4][4];
#pragma unroll
  for (int i = 0; i < 4; ++i)
#pragma unroll
    for (int j = 0; j < 4; ++j) acc[i][j] = (f32x4){0.f, 0.f, 0.f, 0.f};

  for (int kt = 0; kt < K; kt += 32) {
    __syncthreads();
#pragma unroll
    for (int i = 0; i < 2; ++i) {
      int c = tid + i * 256;
      int row = c >> 2;
      int kc = (c & 3) * 8;
      if (A_SCALED_F32) {
        const float* Af = (const float*)Aptr;
        const float* ap = Af + (size_t)(m0 + row) * ldA + kt + kc;
        float4 fa = *(const float4*)ap;
        float4 fb = *(const float4*)(ap + 4);
        float sc = invden[(size_t)(m0 + row) * 16 + ((kt + kc) >> 7)];
        uint2 q0, q1;
        q0.x = (unsigned)f2bf(fa.x * sc) | ((unsigned)f2bf(fa.y * sc) << 16);
        q0.y = (unsigned)f2bf(fa.z * sc) | ((unsigned)f2bf(fa.w * sc) << 16);
        q1.x = (unsigned)f2bf(fb.x * sc) | ((unsigned)f2bf(fb.y * sc) << 16);
        q1.y = (unsigned)f2bf(fb.z * sc) | ((unsigned)f2bf(fb.w * sc) << 16);
        *(uint2*)&As[row][kc] = q0;
        *(uint2*)&As[row][kc + 4] = q1;
      } else {
        const unsigned short* Ab = (const unsigned short*)Aptr;
        *(int4*)&As[row][kc] = *(const int4*)(Ab + (size_t)(m0 + row) * ldA + kt + kc);
      }
      *(int4*)&Bs[row][kc] = *(const int4*)(Bt + (size_t)(n0 + row) * K + kt + kc);
    }
    __syncthreads();
    short8 af[4], bfr[4];
#pragma unroll
    for (int i = 0; i < 4; ++i)
      af[i] = *(const short8*)&As[wm * 64 + i * 16 + r][q * 8];
#pragma unroll
    for (int j = 0; j < 4; ++j)
      bfr[j] = *(const short8*)&Bs[wn * 64 + j * 16 + r][q * 8];
#pragma unroll
    for (int i = 0; i < 4; ++i)
#pragma unroll
      for (int j = 0; j < 4; ++j)
        acc[i][j] = __builtin_amdgcn_mfma_f32_16x16x32_bf16(af[i], bfr[j], acc[i][j], 0, 0, 0);
  }
#pragma unroll
  for (int i = 0; i < 4; ++i) {
#pragma unroll
    for (int j = 0; j < 4; ++j) {
#pragma unroll
      for (int rr = 0; rr < 4; ++rr) {
        int mi = m0 + wm * 64 + i * 16 + q * 4 + rr;
        int ni = n0 + wn * 64 + j * 16 + r;
        float val = acc[i][j][rr];
        if (ADD_BIAS) val += bias[ni];
        if (OUT_BF16)
          ((unsigned short*)Cptr)[(size_t)mi * ldC + ni] = f2bf(val);
        else
          ((float*)Cptr)[(size_t)mi * ldC + ni] = val;
      }
    }
  }
}

// ---------------- prep: G-scan + RoPE + phi + scale + transpose + intra-chunk A ----------------
// grid (32 ch, 32 bh), 256 threads.
__global__ __launch_bounds__(256)
void k_prep(const unsigned short* __restrict__ qkv, const float* __restrict__ beta,
            unsigned short* __restrict__ Qt, unsigned short* __restrict__ Ktg,
            unsigned short* __restrict__ Ag) {
  const int ch = blockIdx.x;
  const int bh = blockIdx.y;
  const int b = bh >> 4, h = bh & 15;
  const int tid = threadIdx.x;
  const int t0 = ch * 64;

  __shared__ float Gs[64];
  __shared__ unsigned short Qs[64][136];
  __shared__ unsigned short Ks[64][136];

  // inclusive prefix product of beta over the chunk (wave 0)
  if (tid < 64) {
    float bb = beta[((size_t)(b * 2048 + t0 + tid)) * 16 + h];
#pragma unroll
    for (int off = 1; off < 64; off <<= 1) {
      float o = __shfl_up(bb, off, 64);
      if (tid >= off) bb *= o;
    }
    Gs[tid] = bb;
  }
  __syncthreads();

  // rope + phi + scale; write Qt (global + LDS), K~ (LDS only)
  const int dgl = tid & 7;
  float invf[8], e_s[8] /*unused placeholder*/;
  (void)e_s;
#pragma unroll
  for (int j = 0; j < 8; ++j)
    invf[j] = expf((float)(dgl * 8 + j) * -0.14391156831212787f);  // 10000^(-e/64)

  int s = tid >> 3;  // 0..31, then +32
#pragma unroll
  for (int rep = 0; rep < 2; ++rep, s += 32) {
    size_t row = ((size_t)(b * 2048 + t0 + s)) * 6144 + (size_t)h * 128;
    short8 qlo = *(const short8*)(qkv + row + dgl * 8);
    short8 qhi = *(const short8*)(qkv + row + 64 + dgl * 8);
    short8 klo = *(const short8*)(qkv + row + 2048 + dgl * 8);
    short8 khi = *(const short8*)(qkv + row + 2048 + 64 + dgl * 8);
    float g = Gs[s];
    float ig = 1.f / g;
    float tg = (float)(t0 + s);
    short8 oql, oqh, okl, okh;
#pragma unroll
    for (int j = 0; j < 8; ++j) {
      float sn, cs;
      __sincosf(tg * invf[j], &sn, &cs);
      float qe = bf2f((unsigned short)qlo[j]), qo = bf2f((unsigned short)qhi[j]);
      float a0 = qe * cs - qo * sn, a1 = qe * sn + qo * cs;
      oql[j] = (short)f2bf(phi_elu1(a0) * g);
      oqh[j] = (short)f2bf(phi_elu1(a1) * g);
      float ke = bf2f((unsigned short)klo[j]), ko = bf2f((unsigned short)khi[j]);
      a0 = ke * cs - ko * sn;
      a1 = ke * sn + ko * cs;
      okl[j] = (short)f2bf(phi_elu1(a0) * ig);
      okh[j] = (short)f2bf(phi_elu1(a1) * ig);
    }
    size_t qbase = (((size_t)bh * 32 + ch) * 64 + s) * 128;
    *(short8*)(Qt + qbase + dgl * 8) = oql;
    *(short8*)(Qt + qbase + 64 + dgl * 8) = oqh;
    *(short8*)&Qs[s][dgl * 8] = oql;
    *(short8*)&Qs[s][64 + dgl * 8] = oqh;
    *(short8*)&Ks[s][dgl * 8] = okl;
    *(short8*)&Ks[s][64 + dgl * 8] = okh;
  }
  __syncthreads();

  // K~^T write-out (coalesced): thread -> d = tid>>1, s-half = tid&1
  {
    const int d = tid >> 1, sh = tid & 1;
    unsigned pk[16];
#pragma unroll
    for (int i = 0; i < 16; ++i)
      pk[i] = (unsigned)Ks[sh * 32 + 2 * i][d] | ((unsigned)Ks[sh * 32 + 2 * i + 1][d] << 16);
    unsigned short* kr = Ktg + ((size_t)bh * 32 + ch) * 8192 + (size_t)d * 64 + sh * 32;
#pragma unroll
    for (int i = 0; i < 4; ++i)
      *(uint4*)(kr + i * 8) = *(uint4*)&pk[i * 4];
  }

  // A = tril(Qs Ks^T), 4 waves x 4 N-tiles, K=128 (4 ksteps)
  {
    const int lane = tid & 63;
    const int w = tid >> 6;
    const int q = lane >> 4, r = lane & 15;
    f32x4 acc[4];
#pragma unroll
    for (int nt = 0; nt < 4; ++nt) acc[nt] = (f32x4){0.f, 0.f, 0.f, 0.f};
#pragma unroll
    for (int kk = 0; kk < 4; ++kk) {
      short8 af = *(const short8*)&Qs[w * 16 + r][kk * 32 + q * 8];
#pragma unroll
      for (int nt = 0; nt < 4; ++nt) {
        short8 bf = *(const short8*)&Ks[nt * 16 + r][kk * 32 + q * 8];
        acc[nt] = __builtin_amdgcn_mfma_f32_16x16x32_bf16(af, bf, acc[nt], 0, 0, 0);
      }
    }
    unsigned short* Agp = Ag + ((size_t)bh * 32 + ch) * 4096;
#pragma unroll
    for (int nt = 0; nt < 4; ++nt) {
#pragma unroll
      for (int rr = 0; rr < 4; ++rr) {
        int t_l = w * 16 + q * 4 + rr;
        int s_l = nt * 16 + r;
        float val = (s_l <= t_l) ? acc[nt][rr] : 0.f;
        Agp[t_l * 64 + s_l] = f2bf(val);
      }
    }
  }
}

// ---------------- chunk scan: numer = A V + Qt S0 ; S = gC (S0 + Kt^T V) ----------------
// grid (9 eb, 32 bh), 256 threads (4 waves). eb==8 is the z/denominator block.
__global__ __launch_bounds__(256)
void k_scan(const unsigned short* __restrict__ Qt, const unsigned short* __restrict__ Ktg,
            const unsigned short* __restrict__ Ag, const unsigned short* __restrict__ qkv,
            const float* __restrict__ beta, float* __restrict__ numer,
            float* __restrict__ invd) {
  const int eb = blockIdx.x;
  const int bh = blockIdx.y;
  const int b = bh >> 4, h = bh & 15;
  const int tid = threadIdx.x;
  const int lane = tid & 63;
  const int w = tid >> 6;
  const int q = lane >> 4, r = lane & 15;
  const int e0 = eb * 16;

  __shared__ unsigned short Qs[64][136];
  __shared__ unsigned short Kts[128][72];
  __shared__ unsigned short As[64][72];
  __shared__ unsigned short Vt[16][72];
  __shared__ unsigned short Sb[128][18];

  f32x4 S_acc[2];
  S_acc[0] = (f32x4){0.f, 0.f, 0.f, 0.f};
  S_acc[1] = (f32x4){0.f, 0.f, 0.f, 0.f};

  for (int ch = 0; ch < 32; ++ch) {
    __syncthreads();  // previous chunk's LDS reads done
    // ---- stage ----
    {
      const unsigned short* Qg = Qt + ((size_t)bh * 32 + ch) * 8192;
#pragma unroll
      for (int i = 0; i < 4; ++i) {
        int c = tid + i * 256;
        int ss = c >> 4, dg = c & 15;
        *(int4*)&Qs[ss][dg * 8] = *(const int4*)(Qg + ss * 128 + dg * 8);
      }
      const unsigned short* Kg = Ktg + ((size_t)bh * 32 + ch) * 8192;
#pragma unroll
      for (int i = 0; i < 4; ++i) {
        int c = tid + i * 256;
        int d = c >> 3, sg = c & 7;
        *(int4*)&Kts[d][sg * 8] = *(const int4*)(Kg + d * 64 + sg * 8);
      }
      const unsigned short* Agp = Ag + ((size_t)bh * 32 + ch) * 4096;
#pragma unroll
      for (int i = 0; i < 2; ++i) {
        int c = tid + i * 256;
        int t_l = c >> 3, sg = c & 7;
        *(int4*)&As[t_l][sg * 8] = *(const int4*)(Agp + t_l * 64 + sg * 8);
      }
      if (eb < 8) {
        int ss = tid >> 2, e4 = tid & 3;
        const unsigned short* vp =
            qkv + ((size_t)(b * 2048 + ch * 64 + ss)) * 6144 + 4096 + h * 128 + e0 + e4 * 4;
        uint2 vv = *(const uint2*)vp;
        const unsigned short* pv = (const unsigned short*)&vv;
#pragma unroll
        for (int j = 0; j < 4; ++j) Vt[e4 * 4 + j][ss] = pv[j];
      } else {
        int e = tid >> 4, s4 = (tid & 15) * 4;
#pragma unroll
        for (int j = 0; j < 4; ++j) Vt[e][s4 + j] = (e == 0) ? (unsigned short)0x3F80 : (unsigned short)0;
      }
      // S0 -> bf16 for the numer matmul
#pragma unroll
      for (int i = 0; i < 2; ++i)
#pragma unroll
        for (int rr = 0; rr < 4; ++rr)
          Sb[(2 * w + i) * 16 + q * 4 + rr][r] = f2bf(S_acc[i][rr]);
    }
    __syncthreads();

    // gC = product of chunk betas (wave-redundant)
    float gc;
    {
      float bl = beta[((size_t)(b * 2048 + ch * 64 + lane)) * 16 + h];
#pragma unroll
      for (int off = 1; off < 64; off <<= 1) bl *= __shfl_xor(bl, off, 64);
      gc = bl;
    }

    // numer tile (wave w owns rows w*16..w*16+15): Qt*S0 + A*V
    f32x4 nacc = (f32x4){0.f, 0.f, 0.f, 0.f};
#pragma unroll
    for (int kk = 0; kk < 4; ++kk) {
      short8 af = *(const short8*)&Qs[w * 16 + r][kk * 32 + q * 8];
      short8 bf;
#pragma unroll
      for (int j = 0; j < 8; ++j) bf[j] = (short)Sb[kk * 32 + q * 8 + j][r];
      nacc = __builtin_amdgcn_mfma_f32_16x16x32_bf16(af, bf, nacc, 0, 0, 0);
    }
    short8 vf[2];
#pragma unroll
    for (int kk = 0; kk < 2; ++kk) {
      vf[kk] = *(const short8*)&Vt[r][kk * 32 + q * 8];
      short8 af = *(const short8*)&As[w * 16 + r][kk * 32 + q * 8];
      nacc = __builtin_amdgcn_mfma_f32_16x16x32_bf16(af, vf[kk], nacc, 0, 0, 0);
    }
#pragma unroll
    for (int rr = 0; rr < 4; ++rr) {
      int t_l = w * 16 + q * 4 + rr;
      size_t m = (size_t)b * 2048 + ch * 64 + t_l;
      if (eb < 8)
        numer[m * 2048 + h * 128 + e0 + r] = nacc[rr];
      else if (r == 0)
        invd[m * 16 + h] = 1.f / (nacc[rr] + 1e-6f);
    }

    // state update: S = gC * (S0 + Kt^T V), fp32 accumulate
#pragma unroll
    for (int i = 0; i < 2; ++i) {
#pragma unroll
      for (int kk = 0; kk < 2; ++kk) {
        short8 af = *(const short8*)&Kts[(2 * w + i) * 16 + r][kk * 32 + q * 8];
        S_acc[i] = __builtin_amdgcn_mfma_f32_16x16x32_bf16(af, vf[kk], S_acc[i], 0, 0, 0);
      }
#pragma unroll
      for (int rr = 0; rr < 4; ++rr) S_acc[i][rr] *= gc;
    }
  }
}

extern "C" void kernel_launch(void* const* d_in, const int* in_sizes, int n_in,
                              void* d_out, int out_size, void* d_ws, size_t ws_size,
                              hipStream_t stream) {
  const float* x  = (const float*)d_in[0];
  const float* Wq = (const float*)d_in[1];
  const float* Wk = (const float*)d_in[2];
  const float* Wv = (const float*)d_in[3];
  const float* Wg = (const float*)d_in[4];
  const float* bg = (const float*)d_in[5];
  const float* Wo = (const float*)d_in[6];
  const float* bo = (const float*)d_in[7];

  // workspace layout (bytes), total 134,742,016 (same as validated round 0)
  char* ws = (char*)d_ws;
  unsigned short* xb    = (unsigned short*)(ws);                 // 16,777,216  x bf16 [4096][2048]
  unsigned short* Qt    = (unsigned short*)(ws);                 // reuses xb after QKV gemm
  unsigned short* Wt    = (unsigned short*)(ws + 16777216);      // 25,165,824  [6144][2048]
  unsigned short* Ktg   = (unsigned short*)(ws + 16777216);      // reuses Wt: 16,777,216
  unsigned short* Ag    = (unsigned short*)(ws + 33554432);      // reuses Wt:  8,388,608
  unsigned short* Wot   = (unsigned short*)(ws + 41943040);      //  8,388,608  [2048][2048]
  unsigned short* qkvb  = (unsigned short*)(ws + 50331648);      // 50,331,648  [4096][6144]
  float*          beta  = (float*)(ws + 100663296);              //    262,144  [4096][16]
  float*          invd  = (float*)(ws + 100925440);              //    262,144  [4096][16]
  float*          numer = (float*)(ws + 101187584);              // 33,554,432  [4096][2048] fp32

  k_cast<<<8192, 256, 0, stream>>>(x, xb);
  k_transw<<<dim3(32, 32, 4), 256, 0, stream>>>(Wq, Wk, Wv, Wo, Wt, Wot);
  k_beta<<<4096, 256, 0, stream>>>(x, Wg, bg, beta);
  k_gemm<false, true, false><<<dim3(48, 32), 256, 0, stream>>>(
      xb, Wt, qkvb, nullptr, nullptr, 4096, 6144, 2048, 2048, 6144);
  k_prep<<<dim3(32, 32), 256, 0, stream>>>(qkvb, beta, Qt, Ktg, Ag);
  k_scan<<<dim3(9, 32), 256, 0, stream>>>(Qt, Ktg, Ag, qkvb, beta, numer, invd);
  k_gemm<true, false, true><<<dim3(16, 32), 256, 0, stream>>>(
      numer, Wot, d_out, invd, bo, 4096, 2048, 2048, 2048, 2048);
}